// Round 1
// 461.567 us; speedup vs baseline: 1.7048x; 1.7048x over previous
//
#include <hip/hip_runtime.h>
#include <hip/hip_bf16.h>

// GCN 2-layer: out = (Â relu(Â (x@W1) + b1)) @ W2 + b2,  Â = D^-1/2 (A+I) D^-1/2
// N=100000, E=3200000, dims 128 -> 32 -> 16, fp32.
// Round 3: bucketed CSR build (2-level radix partition) replaces the random
// 4B-scatter fill_csr (was 275us, 194MB write-allocate traffic).
//   P1: coarse-bucket histogram (LDS-aggregated)
//   scan: 1-wave exclusive scan of 391 bucket counts
//   P2: partition edges into buckets as packed u32 (src | dstLocal<<17),
//       per-WG LDS histogram + chunk reservation -> ~40B contiguous runs
//   P3: per-bucket local CSR (LDS count/scan/scatter into 32KB region)
// Also: inv[] is ready before gemm1 now, so xw/hw are pre-scaled by inv[row],
// removing the random inv[s] gather from both aggregation inner loops.

#define IN_DIM 128
#define HID1 32
#define HID2 16

#define BSHIFT 8                 // 256 nodes per coarse bucket
#define MAXNB 1024               // supports N <= 262144 (and src<2^17 packing: N <= 131072)
#define P2_TILE 4096             // edges per workgroup in partition pass
#define P2_PER_THREAD 16

// ---------------------------------------------------------------------------
// Edge dtype probe (reference says int64; default JAX gives int32).
__global__ void detect_fmt(const int* __restrict__ e32, int* __restrict__ flag) {
    if (blockIdx.x == 0 && threadIdx.x == 0) {
        int is64 = 1;
        for (int i = 0; i < 64; ++i)
            if (e32[2 * i + 1] != 0) { is64 = 0; break; }
        *flag = is64;
    }
}

__device__ __forceinline__ void load_edge(const int* __restrict__ e32, int is64,
                                          long e, long E, int& s, int& d) {
    if (is64) { s = e32[2 * e];  d = e32[2 * E + 2 * e]; }
    else      { s = e32[e];      d = e32[E + e]; }
}

__device__ __forceinline__ int load_dst(const int* __restrict__ e32, int is64,
                                        long e, long E) {
    return is64 ? e32[2 * E + 2 * e] : e32[E + e];
}

// ---------------------------------------------------------------------------
__global__ void init_buckets(int* __restrict__ bucketCnt, int NB) {
    int i = blockIdx.x * blockDim.x + threadIdx.x;
    if (i < NB) bucketCnt[i] = 0;
}

// P1: count edges per coarse bucket, LDS-aggregated.
__global__ __launch_bounds__(256) void count_buckets(const int* __restrict__ e32,
                                                     const int* __restrict__ flag,
                                                     int* __restrict__ bucketCnt,
                                                     int E, int NB) {
    __shared__ int hist[MAXNB];
    for (int i = threadIdx.x; i < NB; i += 256) hist[i] = 0;
    __syncthreads();
    int is64 = *flag;
    long stride = (long)gridDim.x * blockDim.x;
    for (long e = blockIdx.x * (long)blockDim.x + threadIdx.x; e < E; e += stride) {
        int d = load_dst(e32, is64, e, E);
        atomicAdd(&hist[d >> BSHIFT], 1);
    }
    __syncthreads();
    for (int i = threadIdx.x; i < NB; i += 256)
        if (hist[i]) atomicAdd(&bucketCnt[i], hist[i]);
}

// Exclusive scan of NB (<=1024) bucket counts; one wave, 16 buckets/lane.
__global__ void scan_buckets(const int* __restrict__ bucketCnt,
                             int* __restrict__ bucketStart,
                             int* __restrict__ bucketCursor, int NB) {
    int lane = threadIdx.x;   // 0..63
    int c[16];
    int sum = 0;
#pragma unroll
    for (int k = 0; k < 16; ++k) {
        int idx = lane * 16 + k;
        c[k] = (idx < NB) ? bucketCnt[idx] : 0;
        sum += c[k];
    }
    int s = sum;
#pragma unroll
    for (int off = 1; off < 64; off <<= 1) {
        int t = __shfl_up(s, off, 64);
        if (lane >= off) s += t;
    }
    int run = s - sum;   // exclusive prefix
#pragma unroll
    for (int k = 0; k < 16; ++k) {
        int idx = lane * 16 + k;
        if (idx < NB) { bucketStart[idx] = run; bucketCursor[idx] = run; }
        run += c[k];
    }
    if (lane == 63) bucketStart[NB] = s;   // == E
}

// P2: partition edges into coarse buckets as packed u32 (src | dstLocal<<17).
// Per-WG: LDS histogram -> chunk reservation -> contiguous-run writes.
__global__ __launch_bounds__(256) void partition_edges(const int* __restrict__ e32,
                                                       const int* __restrict__ flag,
                                                       int* __restrict__ bucketCursor,
                                                       unsigned int* __restrict__ part,
                                                       int E, int NB) {
    __shared__ int lbase[MAXNB];   // histogram, then global-base cursor
    for (int i = threadIdx.x; i < NB; i += 256) lbase[i] = 0;
    __syncthreads();
    int is64 = *flag;
    long e0 = (long)blockIdx.x * P2_TILE;
    unsigned int v[P2_PER_THREAD];
    int bb[P2_PER_THREAD];
#pragma unroll
    for (int i = 0; i < P2_PER_THREAD; ++i) {
        long e = e0 + threadIdx.x + i * 256;
        if (e < E) {
            int s, d;
            load_edge(e32, is64, e, E, s, d);
            bb[i] = d >> BSHIFT;
            v[i] = (unsigned int)s | ((unsigned int)(d & ((1 << BSHIFT) - 1)) << 17);
            atomicAdd(&lbase[bb[i]], 1);
        } else {
            bb[i] = -1;
        }
    }
    __syncthreads();
    // reserve one contiguous chunk per non-empty bucket
    for (int i = threadIdx.x; i < NB; i += 256) {
        int c = lbase[i];
        lbase[i] = c ? atomicAdd(&bucketCursor[i], c) : 0;
    }
    __syncthreads();
#pragma unroll
    for (int i = 0; i < P2_PER_THREAD; ++i) {
        if (bb[i] >= 0) {
            int pos = atomicAdd(&lbase[bb[i]], 1);
            part[pos] = v[i];
        }
    }
}

// P3: one WG per bucket. Local per-node count, scan, scatter srcs into the
// bucket's contiguous (L2-resident) region. Emits rowStart/cnt/inv.
__global__ __launch_bounds__(256) void build_rows(const unsigned int* __restrict__ part,
                                                  const int* __restrict__ bucketStart,
                                                  int* __restrict__ rowStart,
                                                  int* __restrict__ cnt,
                                                  float* __restrict__ inv,
                                                  int* __restrict__ srcs, int N) {
    int b = blockIdx.x;
    int beg = bucketStart[b];
    int end = bucketStart[b + 1];
    __shared__ int lc[256];     // local counts
    __shared__ int lofs[256];   // global cursor per local node
    __shared__ int wsum[4];
    int tid = threadIdx.x;
    lc[tid] = 0;
    __syncthreads();
    for (int i = beg + tid; i < end; i += 256)
        atomicAdd(&lc[part[i] >> 17], 1);
    __syncthreads();
    int c = lc[tid];
    int s = c;
#pragma unroll
    for (int off = 1; off < 64; off <<= 1) {
        int t = __shfl_up(s, off, 64);
        if ((tid & 63) >= off) s += t;
    }
    if ((tid & 63) == 63) wsum[tid >> 6] = s;
    __syncthreads();
    int wb = 0;
    for (int w = 0; w < (tid >> 6); ++w) wb += wsum[w];
    int gstart = beg + wb + s - c;   // exclusive scan + bucket base
    int n = (b << BSHIFT) + tid;
    if (n < N) {
        rowStart[n] = gstart;
        cnt[n] = c;
        inv[n] = rsqrtf((float)(c + 1));
    }
    lofs[tid] = gstart;
    __syncthreads();
    for (int i = beg + tid; i < end; i += 256) {
        unsigned int v = part[i];
        int pos = atomicAdd(&lofs[v >> 17], 1);
        srcs[pos] = (int)(v & 0x1FFFF);
    }
}

// ---------------------------------------------------------------------------
// xw = (x @ W1) * inv[row]   (x: [N,128], W1: [128,32]; pre-scaled by inv)
__global__ __launch_bounds__(256) void gemm1(const float* __restrict__ x,
                                             const float* __restrict__ W1,
                                             const float* __restrict__ inv,
                                             float* __restrict__ xw, int N) {
    __shared__ float sW[IN_DIM * HID1];  // 16 KB
    __shared__ float sX[8 * IN_DIM];     // 4 KB
    for (int i = threadIdx.x; i < IN_DIM * HID1 / 4; i += 256)
        ((float4*)sW)[i] = ((const float4*)W1)[i];

    int row0 = blockIdx.x * 8;
    {
        int rr = threadIdx.x / 32;
        int kk = (threadIdx.x % 32) * 4;
        int grow = row0 + rr;
        float4 v = make_float4(0.f, 0.f, 0.f, 0.f);
        if (grow < N) v = *(const float4*)&x[(size_t)grow * IN_DIM + kk];
        *(float4*)&sX[rr * IN_DIM + kk] = v;
    }
    __syncthreads();

    int col = threadIdx.x % HID1;
    int lr  = threadIdx.x / HID1;
    int grow = row0 + lr;
    if (grow >= N) return;
    float acc = 0.f;
#pragma unroll
    for (int k = 0; k < IN_DIM; ++k)
        acc += sX[lr * IN_DIM + k] * sW[k * HID1 + col];
    xw[(size_t)grow * HID1 + col] = acc * inv[grow];
}

// ---------------------------------------------------------------------------
// Layer-1 aggregate: one 64-lane wave per node; 2 edges x 32 channels / iter.
// xw pre-scaled: agg1[n][c] = relu( b1[c] + inv[n] * ( xws[n][c] + Σ_e xws[s][c] ) )
__global__ __launch_bounds__(256) void agg1_k(const int* __restrict__ rowStart,
                                              const int* __restrict__ cnt,
                                              const int* __restrict__ srcs,
                                              const float* __restrict__ inv,
                                              const float* __restrict__ xw,
                                              const float* __restrict__ b1,
                                              float* __restrict__ agg1, int N) {
    int wave = (blockIdx.x * blockDim.x + threadIdx.x) >> 6;
    int lane = threadIdx.x & 63;
    if (wave >= N) return;
    int n = wave;
    int c    = lane & 31;
    int half = lane >> 5;          // 0 or 1
    int start = rowStart[n];
    int len   = cnt[n];
    float invn = inv[n];
    float acc = (half == 0) ? xw[(size_t)n * HID1 + c] : 0.f;
    for (int j = half; j < len; j += 2) {
        int s = srcs[start + j];
        acc += xw[(size_t)s * HID1 + c];
    }
    acc += __shfl_down(acc, 32, 64);   // fold half 1 into half 0
    if (half == 0) {
        float v = b1[c] + invn * acc;
        agg1[(size_t)n * HID1 + c] = fmaxf(v, 0.f);   // ReLU folded
    }
}

// hw = (agg1 @ W2) * inv[row]   (agg1 already ReLU'd; [N,32] @ [32,16])
__global__ __launch_bounds__(256) void gemm2(const float* __restrict__ h,
                                             const float* __restrict__ W2,
                                             const float* __restrict__ inv,
                                             float* __restrict__ hw, int N) {
    __shared__ float sW[HID1 * HID2];  // 2 KB
    for (int i = threadIdx.x; i < HID1 * HID2; i += 256) sW[i] = W2[i];
    __syncthreads();

    int col = threadIdx.x % HID2;
    int lr  = threadIdx.x / HID2;  // 16 rows per block
    int grow = blockIdx.x * 16 + lr;
    if (grow >= N) return;
    float acc = 0.f;
#pragma unroll
    for (int c = 0; c < HID1; ++c)
        acc += h[(size_t)grow * HID1 + c] * sW[c * HID2 + col];
    hw[(size_t)grow * HID2 + col] = acc * inv[grow];
}

// Layer-2 aggregate: one wave per node; 4 edges x 16 channels / iter.
__global__ __launch_bounds__(256) void agg2_k(const int* __restrict__ rowStart,
                                              const int* __restrict__ cnt,
                                              const int* __restrict__ srcs,
                                              const float* __restrict__ inv,
                                              const float* __restrict__ hw,
                                              const float* __restrict__ b2,
                                              float* __restrict__ out, int N) {
    int wave = (blockIdx.x * blockDim.x + threadIdx.x) >> 6;
    int lane = threadIdx.x & 63;
    if (wave >= N) return;
    int n = wave;
    int c = lane & 15;
    int q = lane >> 4;             // 0..3
    int start = rowStart[n];
    int len   = cnt[n];
    float invn = inv[n];
    float acc = (q == 0) ? hw[(size_t)n * HID2 + c] : 0.f;
    for (int j = q; j < len; j += 4) {
        int s = srcs[start + j];
        acc += hw[(size_t)s * HID2 + c];
    }
    acc += __shfl_down(acc, 32, 64);   // q0+=q2, q1+=q3
    acc += __shfl_down(acc, 16, 64);   // q0+=q1
    if (q == 0)
        out[(size_t)n * HID2 + c] = b2[c] + invn * acc;
}

// ---------------------------------------------------------------------------
extern "C" void kernel_launch(void* const* d_in, const int* in_sizes, int n_in,
                              void* d_out, int out_size, void* d_ws, size_t ws_size,
                              hipStream_t stream) {
    const float* x  = (const float*)d_in[0];
    const float* W1 = (const float*)d_in[1];
    const float* b1 = (const float*)d_in[2];
    const float* W2 = (const float*)d_in[3];
    const float* b2 = (const float*)d_in[4];
    const int*  e32 = (const int*)d_in[5];
    float* out = (float*)d_out;

    const int N = in_sizes[0] / IN_DIM;   // 100000
    const int E = in_sizes[5] / 2;        // 3200000
    const int Npad = ((N + 63) / 64) * 64;
    const int Epad = ((E + 63) / 64) * 64;
    const int NB   = (N + (1 << BSHIFT) - 1) >> BSHIFT;   // 391 coarse buckets

    // workspace layout
    char* ws = (char*)d_ws;
    int*   flag         = (int*)ws;                       // 1
    int*   bucketCnt    = (int*)(ws + 256);               // NB   (<=1024)
    int*   bucketStart  = bucketCnt + 1088;               // NB+1
    int*   bucketCursor = bucketStart + 1088;             // NB
    int*   cnt      = bucketCursor + 1088;                // N
    int*   rowStart = cnt + Npad;                         // N
    float* inv      = (float*)(rowStart + Npad);          // N
    int*   srcs     = (int*)(inv + Npad);                 // E
    // part (E u32) aliases xw (N*32 f32): part dead before gemm1 writes xw
    int PXW = Epad > Npad * HID1 ? Epad : Npad * HID1;
    unsigned int* part = (unsigned int*)(srcs + Epad);
    float* xw   = (float*)part;
    float* agg1 = (float*)(srcs + Epad + PXW);            // N*32
    float* hw   = xw;                                     // alias: xw dead after agg1

    detect_fmt<<<1, 64, 0, stream>>>(e32, flag);

    init_buckets<<<(NB + 255) / 256, 256, 0, stream>>>(bucketCnt, NB);
    count_buckets<<<512, 256, 0, stream>>>(e32, flag, bucketCnt, E, NB);
    scan_buckets<<<1, 64, 0, stream>>>(bucketCnt, bucketStart, bucketCursor, NB);
    partition_edges<<<(E + P2_TILE - 1) / P2_TILE, 256, 0, stream>>>(
        e32, flag, bucketCursor, part, E, NB);
    build_rows<<<NB, 256, 0, stream>>>(part, bucketStart, rowStart, cnt, inv, srcs, N);

    gemm1<<<(N + 7) / 8, 256, 0, stream>>>(x, W1, inv, xw, N);
    agg1_k<<<(N + 3) / 4, 256, 0, stream>>>(rowStart, cnt, srcs, inv, xw, b1, agg1, N);

    gemm2<<<(N + 15) / 16, 256, 0, stream>>>(agg1, W2, inv, hw, N);
    agg2_k<<<(N + 3) / 4, 256, 0, stream>>>(rowStart, cnt, srcs, inv, hw, b2, out, N);
}

// Round 2
// 358.828 us; speedup vs baseline: 2.1929x; 1.2863x over previous
//
#include <hip/hip_runtime.h>
#include <hip/hip_bf16.h>

// GCN 2-layer: out = (Â relu(Â (x@W1) + b1)) @ W2 + b2,  Â = D^-1/2 (A+I) D^-1/2
// N=100000, E=3200000, dims 128 -> 32 -> 16, fp32.
// Round 4: MLP-batched aggregation. agg kernels were latency-bound on the
// dependent chain srcs[j] -> xw[srcs[j]] with only 2 gathers in flight per
// wave (147us, 2.8 TB/s effective). Now: per 16-edge chunk, one coalesced
// srcs load + compile-time __shfl broadcasts -> 8 independent gathers in
// flight per half-wave. CSR build (bucketed radix) unchanged from round 3.

#define IN_DIM 128
#define HID1 32
#define HID2 16

#define BSHIFT 8                 // 256 nodes per coarse bucket
#define MAXNB 1024               // supports N <= 131072 (src < 2^17 packing)
#define P2_TILE 4096             // edges per workgroup in partition pass
#define P2_PER_THREAD 16

// ---------------------------------------------------------------------------
// Edge dtype probe (reference says int64; default JAX gives int32).
__global__ void detect_fmt(const int* __restrict__ e32, int* __restrict__ flag) {
    if (blockIdx.x == 0 && threadIdx.x == 0) {
        int is64 = 1;
        for (int i = 0; i < 64; ++i)
            if (e32[2 * i + 1] != 0) { is64 = 0; break; }
        *flag = is64;
    }
}

__device__ __forceinline__ void load_edge(const int* __restrict__ e32, int is64,
                                          long e, long E, int& s, int& d) {
    if (is64) { s = e32[2 * e];  d = e32[2 * E + 2 * e]; }
    else      { s = e32[e];      d = e32[E + e]; }
}

__device__ __forceinline__ int load_dst(const int* __restrict__ e32, int is64,
                                        long e, long E) {
    return is64 ? e32[2 * E + 2 * e] : e32[E + e];
}

// ---------------------------------------------------------------------------
__global__ void init_buckets(int* __restrict__ bucketCnt, int NB) {
    int i = blockIdx.x * blockDim.x + threadIdx.x;
    if (i < NB) bucketCnt[i] = 0;
}

// P1: count edges per coarse bucket, LDS-aggregated.
__global__ __launch_bounds__(256) void count_buckets(const int* __restrict__ e32,
                                                     const int* __restrict__ flag,
                                                     int* __restrict__ bucketCnt,
                                                     int E, int NB) {
    __shared__ int hist[MAXNB];
    for (int i = threadIdx.x; i < NB; i += 256) hist[i] = 0;
    __syncthreads();
    int is64 = *flag;
    long stride = (long)gridDim.x * blockDim.x;
    for (long e = blockIdx.x * (long)blockDim.x + threadIdx.x; e < E; e += stride) {
        int d = load_dst(e32, is64, e, E);
        atomicAdd(&hist[d >> BSHIFT], 1);
    }
    __syncthreads();
    for (int i = threadIdx.x; i < NB; i += 256)
        if (hist[i]) atomicAdd(&bucketCnt[i], hist[i]);
}

// Exclusive scan of NB (<=1024) bucket counts; one wave, 16 buckets/lane.
__global__ void scan_buckets(const int* __restrict__ bucketCnt,
                             int* __restrict__ bucketStart,
                             int* __restrict__ bucketCursor, int NB) {
    int lane = threadIdx.x;   // 0..63
    int c[16];
    int sum = 0;
#pragma unroll
    for (int k = 0; k < 16; ++k) {
        int idx = lane * 16 + k;
        c[k] = (idx < NB) ? bucketCnt[idx] : 0;
        sum += c[k];
    }
    int s = sum;
#pragma unroll
    for (int off = 1; off < 64; off <<= 1) {
        int t = __shfl_up(s, off, 64);
        if (lane >= off) s += t;
    }
    int run = s - sum;   // exclusive prefix
#pragma unroll
    for (int k = 0; k < 16; ++k) {
        int idx = lane * 16 + k;
        if (idx < NB) { bucketStart[idx] = run; bucketCursor[idx] = run; }
        run += c[k];
    }
    if (lane == 63) bucketStart[NB] = s;   // == E
}

// P2: partition edges into coarse buckets as packed u32 (src | dstLocal<<17).
// Per-WG: LDS histogram -> chunk reservation -> contiguous-run writes.
__global__ __launch_bounds__(256) void partition_edges(const int* __restrict__ e32,
                                                       const int* __restrict__ flag,
                                                       int* __restrict__ bucketCursor,
                                                       unsigned int* __restrict__ part,
                                                       int E, int NB) {
    __shared__ int lbase[MAXNB];   // histogram, then global-base cursor
    for (int i = threadIdx.x; i < NB; i += 256) lbase[i] = 0;
    __syncthreads();
    int is64 = *flag;
    long e0 = (long)blockIdx.x * P2_TILE;
    unsigned int v[P2_PER_THREAD];
    int bb[P2_PER_THREAD];
#pragma unroll
    for (int i = 0; i < P2_PER_THREAD; ++i) {
        long e = e0 + threadIdx.x + i * 256;
        if (e < E) {
            int s, d;
            load_edge(e32, is64, e, E, s, d);
            bb[i] = d >> BSHIFT;
            v[i] = (unsigned int)s | ((unsigned int)(d & ((1 << BSHIFT) - 1)) << 17);
            atomicAdd(&lbase[bb[i]], 1);
        } else {
            bb[i] = -1;
        }
    }
    __syncthreads();
    // reserve one contiguous chunk per non-empty bucket
    for (int i = threadIdx.x; i < NB; i += 256) {
        int c = lbase[i];
        lbase[i] = c ? atomicAdd(&bucketCursor[i], c) : 0;
    }
    __syncthreads();
#pragma unroll
    for (int i = 0; i < P2_PER_THREAD; ++i) {
        if (bb[i] >= 0) {
            int pos = atomicAdd(&lbase[bb[i]], 1);
            part[pos] = v[i];
        }
    }
}

// P3: one WG per bucket. Local per-node count, scan, scatter srcs into the
// bucket's contiguous (L2-resident) region. Emits rowStart/cnt/inv.
__global__ __launch_bounds__(256) void build_rows(const unsigned int* __restrict__ part,
                                                  const int* __restrict__ bucketStart,
                                                  int* __restrict__ rowStart,
                                                  int* __restrict__ cnt,
                                                  float* __restrict__ inv,
                                                  int* __restrict__ srcs, int N) {
    int b = blockIdx.x;
    int beg = bucketStart[b];
    int end = bucketStart[b + 1];
    __shared__ int lc[256];     // local counts
    __shared__ int lofs[256];   // global cursor per local node
    __shared__ int wsum[4];
    int tid = threadIdx.x;
    lc[tid] = 0;
    __syncthreads();
    for (int i = beg + tid; i < end; i += 256)
        atomicAdd(&lc[part[i] >> 17], 1);
    __syncthreads();
    int c = lc[tid];
    int s = c;
#pragma unroll
    for (int off = 1; off < 64; off <<= 1) {
        int t = __shfl_up(s, off, 64);
        if ((tid & 63) >= off) s += t;
    }
    if ((tid & 63) == 63) wsum[tid >> 6] = s;
    __syncthreads();
    int wb = 0;
    for (int w = 0; w < (tid >> 6); ++w) wb += wsum[w];
    int gstart = beg + wb + s - c;   // exclusive scan + bucket base
    int n = (b << BSHIFT) + tid;
    if (n < N) {
        rowStart[n] = gstart;
        cnt[n] = c;
        inv[n] = rsqrtf((float)(c + 1));
    }
    lofs[tid] = gstart;
    __syncthreads();
    for (int i = beg + tid; i < end; i += 256) {
        unsigned int v = part[i];
        int pos = atomicAdd(&lofs[v >> 17], 1);
        srcs[pos] = (int)(v & 0x1FFFF);
    }
}

// ---------------------------------------------------------------------------
// xw = (x @ W1) * inv[row]   (x: [N,128], W1: [128,32]; pre-scaled by inv)
__global__ __launch_bounds__(256) void gemm1(const float* __restrict__ x,
                                             const float* __restrict__ W1,
                                             const float* __restrict__ inv,
                                             float* __restrict__ xw, int N) {
    __shared__ float sW[IN_DIM * HID1];  // 16 KB
    __shared__ float sX[8 * IN_DIM];     // 4 KB
    for (int i = threadIdx.x; i < IN_DIM * HID1 / 4; i += 256)
        ((float4*)sW)[i] = ((const float4*)W1)[i];

    int row0 = blockIdx.x * 8;
    {
        int rr = threadIdx.x / 32;
        int kk = (threadIdx.x % 32) * 4;
        int grow = row0 + rr;
        float4 v = make_float4(0.f, 0.f, 0.f, 0.f);
        if (grow < N) v = *(const float4*)&x[(size_t)grow * IN_DIM + kk];
        *(float4*)&sX[rr * IN_DIM + kk] = v;
    }
    __syncthreads();

    int col = threadIdx.x % HID1;
    int lr  = threadIdx.x / HID1;
    int grow = row0 + lr;
    if (grow >= N) return;
    float acc = 0.f;
#pragma unroll
    for (int k = 0; k < IN_DIM; ++k)
        acc += sX[lr * IN_DIM + k] * sW[k * HID1 + col];
    xw[(size_t)grow * HID1 + col] = acc * inv[grow];
}

// ---------------------------------------------------------------------------
// Layer-1 aggregate: one 64-lane wave per node.
// Main loop: 16 edges/chunk -- one coalesced srcs load, then 8 independent
// gathers in flight per 32-lane half (compile-time __shfl broadcasts).
// xw pre-scaled: agg1[n][c] = relu( b1[c] + inv[n] * ( xws[n][c] + Σ_e xws[s][c] ) )
__global__ __launch_bounds__(256) void agg1_k(const int* __restrict__ rowStart,
                                              const int* __restrict__ cnt,
                                              const int* __restrict__ srcs,
                                              const float* __restrict__ inv,
                                              const float* __restrict__ xw,
                                              const float* __restrict__ b1,
                                              float* __restrict__ agg1, int N) {
    int wave = (blockIdx.x * blockDim.x + threadIdx.x) >> 6;
    int lane = threadIdx.x & 63;
    if (wave >= N) return;
    int n = wave;
    int c    = lane & 31;
    int half = lane >> 5;          // 0 or 1
    int start = rowStart[n];
    int len   = cnt[n];
    float invn = inv[n];
    float acc = (half == 0) ? xw[(size_t)n * HID1 + c] : 0.f;

    int j0 = 0;
    for (; j0 + 16 <= len; j0 += 16) {
        int sv = srcs[start + j0 + (lane & 15)];   // coalesced 16-entry chunk
#pragma unroll
        for (int t = 0; t < 8; ++t) {
            int s = __shfl(sv, half + 2 * t, 64);  // compile-time lane index
            acc += xw[(size_t)s * HID1 + c];       // 8 independent gathers
        }
    }
    for (int j = j0 + half; j < len; j += 2) {     // remainder (<16 edges)
        int s = srcs[start + j];
        acc += xw[(size_t)s * HID1 + c];
    }

    acc += __shfl_down(acc, 32, 64);   // fold half 1 into half 0
    if (half == 0) {
        float v = b1[c] + invn * acc;
        agg1[(size_t)n * HID1 + c] = fmaxf(v, 0.f);   // ReLU folded
    }
}

// hw = (agg1 @ W2) * inv[row]   (agg1 already ReLU'd; [N,32] @ [32,16])
__global__ __launch_bounds__(256) void gemm2(const float* __restrict__ h,
                                             const float* __restrict__ W2,
                                             const float* __restrict__ inv,
                                             float* __restrict__ hw, int N) {
    __shared__ float sW[HID1 * HID2];  // 2 KB
    for (int i = threadIdx.x; i < HID1 * HID2; i += 256) sW[i] = W2[i];
    __syncthreads();

    int col = threadIdx.x % HID2;
    int lr  = threadIdx.x / HID2;  // 16 rows per block
    int grow = blockIdx.x * 16 + lr;
    if (grow >= N) return;
    float acc = 0.f;
#pragma unroll
    for (int c = 0; c < HID1; ++c)
        acc += h[(size_t)grow * HID1 + c] * sW[c * HID2 + col];
    hw[(size_t)grow * HID2 + col] = acc * inv[grow];
}

// Layer-2 aggregate: one wave per node; quarter-split (16 ch), same chunked
// MLP batching: 16 edges/chunk, 4 independent gathers in flight per quarter.
__global__ __launch_bounds__(256) void agg2_k(const int* __restrict__ rowStart,
                                              const int* __restrict__ cnt,
                                              const int* __restrict__ srcs,
                                              const float* __restrict__ inv,
                                              const float* __restrict__ hw,
                                              const float* __restrict__ b2,
                                              float* __restrict__ out, int N) {
    int wave = (blockIdx.x * blockDim.x + threadIdx.x) >> 6;
    int lane = threadIdx.x & 63;
    if (wave >= N) return;
    int n = wave;
    int c = lane & 15;
    int q = lane >> 4;             // 0..3
    int start = rowStart[n];
    int len   = cnt[n];
    float invn = inv[n];
    float acc = (q == 0) ? hw[(size_t)n * HID2 + c] : 0.f;

    int j0 = 0;
    for (; j0 + 16 <= len; j0 += 16) {
        int sv = srcs[start + j0 + (lane & 15)];
#pragma unroll
        for (int t = 0; t < 4; ++t) {
            int s = __shfl(sv, q + 4 * t, 64);
            acc += hw[(size_t)s * HID2 + c];
        }
    }
    for (int j = j0 + q; j < len; j += 4) {
        int s = srcs[start + j];
        acc += hw[(size_t)s * HID2 + c];
    }

    acc += __shfl_down(acc, 32, 64);   // q0+=q2, q1+=q3
    acc += __shfl_down(acc, 16, 64);   // q0+=q1
    if (q == 0)
        out[(size_t)n * HID2 + c] = b2[c] + invn * acc;
}

// ---------------------------------------------------------------------------
extern "C" void kernel_launch(void* const* d_in, const int* in_sizes, int n_in,
                              void* d_out, int out_size, void* d_ws, size_t ws_size,
                              hipStream_t stream) {
    const float* x  = (const float*)d_in[0];
    const float* W1 = (const float*)d_in[1];
    const float* b1 = (const float*)d_in[2];
    const float* W2 = (const float*)d_in[3];
    const float* b2 = (const float*)d_in[4];
    const int*  e32 = (const int*)d_in[5];
    float* out = (float*)d_out;

    const int N = in_sizes[0] / IN_DIM;   // 100000
    const int E = in_sizes[5] / 2;        // 3200000
    const int Npad = ((N + 63) / 64) * 64;
    const int Epad = ((E + 63) / 64) * 64;
    const int NB   = (N + (1 << BSHIFT) - 1) >> BSHIFT;   // 391 coarse buckets

    // workspace layout
    char* ws = (char*)d_ws;
    int*   flag         = (int*)ws;                       // 1
    int*   bucketCnt    = (int*)(ws + 256);               // NB   (<=1024)
    int*   bucketStart  = bucketCnt + 1088;               // NB+1
    int*   bucketCursor = bucketStart + 1088;             // NB
    int*   cnt      = bucketCursor + 1088;                // N
    int*   rowStart = cnt + Npad;                         // N
    float* inv      = (float*)(rowStart + Npad);          // N
    int*   srcs     = (int*)(inv + Npad);                 // E
    // part (E u32) aliases xw (N*32 f32): part dead before gemm1 writes xw
    int PXW = Epad > Npad * HID1 ? Epad : Npad * HID1;
    unsigned int* part = (unsigned int*)(srcs + Epad);
    float* xw   = (float*)part;
    float* agg1 = (float*)(srcs + Epad + PXW);            // N*32
    float* hw   = xw;                                     // alias: xw dead after agg1

    detect_fmt<<<1, 64, 0, stream>>>(e32, flag);

    init_buckets<<<(NB + 255) / 256, 256, 0, stream>>>(bucketCnt, NB);
    count_buckets<<<512, 256, 0, stream>>>(e32, flag, bucketCnt, E, NB);
    scan_buckets<<<1, 64, 0, stream>>>(bucketCnt, bucketStart, bucketCursor, NB);
    partition_edges<<<(E + P2_TILE - 1) / P2_TILE, 256, 0, stream>>>(
        e32, flag, bucketCursor, part, E, NB);
    build_rows<<<NB, 256, 0, stream>>>(part, bucketStart, rowStart, cnt, inv, srcs, N);

    gemm1<<<(N + 7) / 8, 256, 0, stream>>>(x, W1, inv, xw, N);
    agg1_k<<<(N + 3) / 4, 256, 0, stream>>>(rowStart, cnt, srcs, inv, xw, b1, agg1, N);

    gemm2<<<(N + 15) / 16, 256, 0, stream>>>(agg1, W2, inv, hw, N);
    agg2_k<<<(N + 3) / 4, 256, 0, stream>>>(rowStart, cnt, srcs, inv, hw, b2, out, N);
}

// Round 3
// 330.422 us; speedup vs baseline: 2.3814x; 1.0860x over previous
//
#include <hip/hip_runtime.h>
#include <hip/hip_bf16.h>

// GCN 2-layer: out = (Â relu(Â (x@W1) + b1)) @ W2 + b2,  Â = D^-1/2 (A+I) D^-1/2
// N=100000, E=3200000, dims 128 -> 32 -> 16, fp32.
// Round 5: full-row srcs preload + deep-MLP aggregation, gemm2 fused into agg1.
//  - mean degree 32 (sigma~5.7, P(len>64)~0) -> one coalesced 64-lane srcs
//    preload serves the whole row; per-half 4x8 predicated unrolled groups put
//    up to 32 independent gathers in flight (was 8, chained behind a srcs load).
//  - agg1 stages the relu'd row in LDS and computes @W2 in-kernel, writing hw
//    directly: kills the gemm2 dispatch + 25.6 MB of intermediate traffic.
// CSR build (bucketed radix) unchanged from round 3.

#define IN_DIM 128
#define HID1 32
#define HID2 16

#define BSHIFT 8                 // 256 nodes per coarse bucket
#define MAXNB 1024               // supports N <= 131072 (src < 2^17 packing)
#define P2_TILE 4096             // edges per workgroup in partition pass
#define P2_PER_THREAD 16

// ---------------------------------------------------------------------------
// Edge dtype probe (reference says int64; default JAX gives int32).
__global__ void detect_fmt(const int* __restrict__ e32, int* __restrict__ flag) {
    if (blockIdx.x == 0 && threadIdx.x == 0) {
        int is64 = 1;
        for (int i = 0; i < 64; ++i)
            if (e32[2 * i + 1] != 0) { is64 = 0; break; }
        *flag = is64;
    }
}

__device__ __forceinline__ void load_edge(const int* __restrict__ e32, int is64,
                                          long e, long E, int& s, int& d) {
    if (is64) { s = e32[2 * e];  d = e32[2 * E + 2 * e]; }
    else      { s = e32[e];      d = e32[E + e]; }
}

__device__ __forceinline__ int load_dst(const int* __restrict__ e32, int is64,
                                        long e, long E) {
    return is64 ? e32[2 * E + 2 * e] : e32[E + e];
}

// ---------------------------------------------------------------------------
__global__ void init_buckets(int* __restrict__ bucketCnt, int NB) {
    int i = blockIdx.x * blockDim.x + threadIdx.x;
    if (i < NB) bucketCnt[i] = 0;
}

// P1: count edges per coarse bucket, LDS-aggregated.
__global__ __launch_bounds__(256) void count_buckets(const int* __restrict__ e32,
                                                     const int* __restrict__ flag,
                                                     int* __restrict__ bucketCnt,
                                                     int E, int NB) {
    __shared__ int hist[MAXNB];
    for (int i = threadIdx.x; i < NB; i += 256) hist[i] = 0;
    __syncthreads();
    int is64 = *flag;
    long stride = (long)gridDim.x * blockDim.x;
    for (long e = blockIdx.x * (long)blockDim.x + threadIdx.x; e < E; e += stride) {
        int d = load_dst(e32, is64, e, E);
        atomicAdd(&hist[d >> BSHIFT], 1);
    }
    __syncthreads();
    for (int i = threadIdx.x; i < NB; i += 256)
        if (hist[i]) atomicAdd(&bucketCnt[i], hist[i]);
}

// Exclusive scan of NB (<=1024) bucket counts; one wave, 16 buckets/lane.
__global__ void scan_buckets(const int* __restrict__ bucketCnt,
                             int* __restrict__ bucketStart,
                             int* __restrict__ bucketCursor, int NB) {
    int lane = threadIdx.x;   // 0..63
    int c[16];
    int sum = 0;
#pragma unroll
    for (int k = 0; k < 16; ++k) {
        int idx = lane * 16 + k;
        c[k] = (idx < NB) ? bucketCnt[idx] : 0;
        sum += c[k];
    }
    int s = sum;
#pragma unroll
    for (int off = 1; off < 64; off <<= 1) {
        int t = __shfl_up(s, off, 64);
        if (lane >= off) s += t;
    }
    int run = s - sum;   // exclusive prefix
#pragma unroll
    for (int k = 0; k < 16; ++k) {
        int idx = lane * 16 + k;
        if (idx < NB) { bucketStart[idx] = run; bucketCursor[idx] = run; }
        run += c[k];
    }
    if (lane == 63) bucketStart[NB] = s;   // == E
}

// P2: partition edges into coarse buckets as packed u32 (src | dstLocal<<17).
// Per-WG: LDS histogram -> chunk reservation -> contiguous-run writes.
__global__ __launch_bounds__(256) void partition_edges(const int* __restrict__ e32,
                                                       const int* __restrict__ flag,
                                                       int* __restrict__ bucketCursor,
                                                       unsigned int* __restrict__ part,
                                                       int E, int NB) {
    __shared__ int lbase[MAXNB];   // histogram, then global-base cursor
    for (int i = threadIdx.x; i < NB; i += 256) lbase[i] = 0;
    __syncthreads();
    int is64 = *flag;
    long e0 = (long)blockIdx.x * P2_TILE;
    unsigned int v[P2_PER_THREAD];
    int bb[P2_PER_THREAD];
#pragma unroll
    for (int i = 0; i < P2_PER_THREAD; ++i) {
        long e = e0 + threadIdx.x + i * 256;
        if (e < E) {
            int s, d;
            load_edge(e32, is64, e, E, s, d);
            bb[i] = d >> BSHIFT;
            v[i] = (unsigned int)s | ((unsigned int)(d & ((1 << BSHIFT) - 1)) << 17);
            atomicAdd(&lbase[bb[i]], 1);
        } else {
            bb[i] = -1;
        }
    }
    __syncthreads();
    // reserve one contiguous chunk per non-empty bucket
    for (int i = threadIdx.x; i < NB; i += 256) {
        int c = lbase[i];
        lbase[i] = c ? atomicAdd(&bucketCursor[i], c) : 0;
    }
    __syncthreads();
#pragma unroll
    for (int i = 0; i < P2_PER_THREAD; ++i) {
        if (bb[i] >= 0) {
            int pos = atomicAdd(&lbase[bb[i]], 1);
            part[pos] = v[i];
        }
    }
}

// P3: one WG per bucket. Local per-node count, scan, scatter srcs into the
// bucket's contiguous (L2-resident) region. Emits rowStart/cnt/inv.
__global__ __launch_bounds__(256) void build_rows(const unsigned int* __restrict__ part,
                                                  const int* __restrict__ bucketStart,
                                                  int* __restrict__ rowStart,
                                                  int* __restrict__ cnt,
                                                  float* __restrict__ inv,
                                                  int* __restrict__ srcs, int N) {
    int b = blockIdx.x;
    int beg = bucketStart[b];
    int end = bucketStart[b + 1];
    __shared__ int lc[256];     // local counts
    __shared__ int lofs[256];   // global cursor per local node
    __shared__ int wsum[4];
    int tid = threadIdx.x;
    lc[tid] = 0;
    __syncthreads();
    for (int i = beg + tid; i < end; i += 256)
        atomicAdd(&lc[part[i] >> 17], 1);
    __syncthreads();
    int c = lc[tid];
    int s = c;
#pragma unroll
    for (int off = 1; off < 64; off <<= 1) {
        int t = __shfl_up(s, off, 64);
        if ((tid & 63) >= off) s += t;
    }
    if ((tid & 63) == 63) wsum[tid >> 6] = s;
    __syncthreads();
    int wb = 0;
    for (int w = 0; w < (tid >> 6); ++w) wb += wsum[w];
    int gstart = beg + wb + s - c;   // exclusive scan + bucket base
    int n = (b << BSHIFT) + tid;
    if (n < N) {
        rowStart[n] = gstart;
        cnt[n] = c;
        inv[n] = rsqrtf((float)(c + 1));
    }
    lofs[tid] = gstart;
    __syncthreads();
    for (int i = beg + tid; i < end; i += 256) {
        unsigned int v = part[i];
        int pos = atomicAdd(&lofs[v >> 17], 1);
        srcs[pos] = (int)(v & 0x1FFFF);
    }
}

// ---------------------------------------------------------------------------
// xw = (x @ W1) * inv[row]   (x: [N,128], W1: [128,32]; pre-scaled by inv)
__global__ __launch_bounds__(256) void gemm1(const float* __restrict__ x,
                                             const float* __restrict__ W1,
                                             const float* __restrict__ inv,
                                             float* __restrict__ xw, int N) {
    __shared__ float sW[IN_DIM * HID1];  // 16 KB
    __shared__ float sX[8 * IN_DIM];     // 4 KB
    for (int i = threadIdx.x; i < IN_DIM * HID1 / 4; i += 256)
        ((float4*)sW)[i] = ((const float4*)W1)[i];

    int row0 = blockIdx.x * 8;
    {
        int rr = threadIdx.x / 32;
        int kk = (threadIdx.x % 32) * 4;
        int grow = row0 + rr;
        float4 v = make_float4(0.f, 0.f, 0.f, 0.f);
        if (grow < N) v = *(const float4*)&x[(size_t)grow * IN_DIM + kk];
        *(float4*)&sX[rr * IN_DIM + kk] = v;
    }
    __syncthreads();

    int col = threadIdx.x % HID1;
    int lr  = threadIdx.x / HID1;
    int grow = row0 + lr;
    if (grow >= N) return;
    float acc = 0.f;
#pragma unroll
    for (int k = 0; k < IN_DIM; ++k)
        acc += sX[lr * IN_DIM + k] * sW[k * HID1 + col];
    xw[(size_t)grow * HID1 + col] = acc * inv[grow];
}

// ---------------------------------------------------------------------------
// Layer-1 aggregate + fused gemm2: one 64-lane wave per node.
// srcs row (len<=64, P(>64)~0) preloaded by all 64 lanes in one coalesced
// load; per-half 4x8 predicated groups -> up to 32 gathers in flight.
// Then relu'd row staged in LDS; 16 lanes compute @W2 and write hw directly.
// hw[n][o] = inv[n] * sum_c relu(b1[c] + inv[n]*(xws[n][c]+sum_e xws[s][c])) * W2[c][o]
__global__ __launch_bounds__(256) void agg1_k(const int* __restrict__ rowStart,
                                              const int* __restrict__ cnt,
                                              const int* __restrict__ srcs,
                                              const float* __restrict__ inv,
                                              const float* __restrict__ xw,
                                              const float* __restrict__ b1,
                                              const float* __restrict__ W2,
                                              float* __restrict__ hw, int N) {
    __shared__ float sW2[HID1 * HID2];   // 2 KB
    __shared__ float sAgg[4][HID1];      // 512 B
    for (int i = threadIdx.x; i < HID1 * HID2; i += 256) sW2[i] = W2[i];

    int w    = threadIdx.x >> 6;         // wave in block
    int lane = threadIdx.x & 63;
    int node = blockIdx.x * 4 + w;
    int n    = node < N ? node : N - 1;  // clamp; no early return (barrier below)
    int c    = lane & 31;
    int half = lane >> 5;                // 0 or 1
    int start = rowStart[n];
    int len   = cnt[n];
    float invn = inv[n];
    float acc = (half == 0) ? xw[(size_t)n * HID1 + c] : 0.f;

    // preload whole srcs row (invalid lanes -> n, always a safe row index)
    int sv = (lane < len) ? srcs[start + lane] : n;
#pragma unroll
    for (int g = 0; g < 4; ++g) {
        int jb = g * 16;
        if (jb < len) {
#pragma unroll
            for (int t = 0; t < 8; ++t) {
                int j = jb + half + 2 * t;
                bool valid = j < len;
                int s = __shfl(sv, valid ? j : 0, 64);
                float v = xw[(size_t)s * HID1 + c];   // always-issued, safe row
                acc += valid ? v : 0.f;
            }
        }
    }
    for (int j = 64 + half; j < len; j += 2)   // ultra-rare tail
        acc += xw[(size_t)srcs[start + j] * HID1 + c];

    acc += __shfl_down(acc, 32, 64);           // fold half 1 into half 0
    if (half == 0)
        sAgg[w][c] = fmaxf(b1[c] + invn * acc, 0.f);   // ReLU folded
    __syncthreads();

    // fused gemm2: 16 lanes per wave, y[o] = sum_c sAgg[w][c] * W2[c][o]
    if (lane < HID2 && node < N) {
        float y = 0.f;
#pragma unroll
        for (int cc = 0; cc < HID1; ++cc)
            y += sAgg[w][cc] * sW2[cc * HID2 + lane];
        hw[(size_t)node * HID2 + lane] = y * invn;   // pre-scale for layer 2
    }
}

// Layer-2 aggregate: one wave per node; quarter-split (16 ch); same full-row
// preload, 4x4 predicated groups -> up to 16 gathers in flight per quarter.
__global__ __launch_bounds__(256) void agg2_k(const int* __restrict__ rowStart,
                                              const int* __restrict__ cnt,
                                              const int* __restrict__ srcs,
                                              const float* __restrict__ inv,
                                              const float* __restrict__ hw,
                                              const float* __restrict__ b2,
                                              float* __restrict__ out, int N) {
    int wave = (blockIdx.x * blockDim.x + threadIdx.x) >> 6;
    int lane = threadIdx.x & 63;
    if (wave >= N) return;
    int n = wave;
    int c = lane & 15;
    int q = lane >> 4;             // 0..3
    int start = rowStart[n];
    int len   = cnt[n];
    float invn = inv[n];
    float acc = (q == 0) ? hw[(size_t)n * HID2 + c] : 0.f;

    int sv = (lane < len) ? srcs[start + lane] : n;
#pragma unroll
    for (int g = 0; g < 4; ++g) {
        int jb = g * 16;
        if (jb < len) {
#pragma unroll
            for (int t = 0; t < 4; ++t) {
                int j = jb + q + 4 * t;
                bool valid = j < len;
                int s = __shfl(sv, valid ? j : 0, 64);
                float v = hw[(size_t)s * HID2 + c];
                acc += valid ? v : 0.f;
            }
        }
    }
    for (int j = 64 + q; j < len; j += 4)   // ultra-rare tail
        acc += hw[(size_t)srcs[start + j] * HID2 + c];

    acc += __shfl_down(acc, 32, 64);   // q0+=q2, q1+=q3
    acc += __shfl_down(acc, 16, 64);   // q0+=q1
    if (q == 0)
        out[(size_t)n * HID2 + c] = b2[c] + invn * acc;
}

// ---------------------------------------------------------------------------
extern "C" void kernel_launch(void* const* d_in, const int* in_sizes, int n_in,
                              void* d_out, int out_size, void* d_ws, size_t ws_size,
                              hipStream_t stream) {
    const float* x  = (const float*)d_in[0];
    const float* W1 = (const float*)d_in[1];
    const float* b1 = (const float*)d_in[2];
    const float* W2 = (const float*)d_in[3];
    const float* b2 = (const float*)d_in[4];
    const int*  e32 = (const int*)d_in[5];
    float* out = (float*)d_out;

    const int N = in_sizes[0] / IN_DIM;   // 100000
    const int E = in_sizes[5] / 2;        // 3200000
    const int Npad = ((N + 63) / 64) * 64;
    const int Epad = ((E + 63) / 64) * 64;
    const int NB   = (N + (1 << BSHIFT) - 1) >> BSHIFT;   // 391 coarse buckets

    // workspace layout
    char* ws = (char*)d_ws;
    int*   flag         = (int*)ws;                       // 1
    int*   bucketCnt    = (int*)(ws + 256);               // NB   (<=1024)
    int*   bucketStart  = bucketCnt + 1088;               // NB+1
    int*   bucketCursor = bucketStart + 1088;             // NB
    int*   cnt      = bucketCursor + 1088;                // N
    int*   rowStart = cnt + Npad;                         // N
    float* inv      = (float*)(rowStart + Npad);          // N
    int*   srcs     = (int*)(inv + Npad);                 // E
    // part (E u32) aliases xw (N*32 f32): part dead before gemm1 writes xw
    int PXW = Epad > Npad * HID1 ? Epad : Npad * HID1;
    unsigned int* part = (unsigned int*)(srcs + Epad);
    float* xw   = (float*)part;
    // hw must NOT alias xw (agg1 reads xw while writing hw) -> old agg1 slot
    float* hw   = (float*)(srcs + Epad + PXW);            // N*16

    detect_fmt<<<1, 64, 0, stream>>>(e32, flag);

    init_buckets<<<(NB + 255) / 256, 256, 0, stream>>>(bucketCnt, NB);
    count_buckets<<<512, 256, 0, stream>>>(e32, flag, bucketCnt, E, NB);
    scan_buckets<<<1, 64, 0, stream>>>(bucketCnt, bucketStart, bucketCursor, NB);
    partition_edges<<<(E + P2_TILE - 1) / P2_TILE, 256, 0, stream>>>(
        e32, flag, bucketCursor, part, E, NB);
    build_rows<<<NB, 256, 0, stream>>>(part, bucketStart, rowStart, cnt, inv, srcs, N);

    gemm1<<<(N + 7) / 8, 256, 0, stream>>>(x, W1, inv, xw, N);
    agg1_k<<<(N + 3) / 4, 256, 0, stream>>>(rowStart, cnt, srcs, inv, xw, b1, W2, hw, N);
    agg2_k<<<(N + 3) / 4, 256, 0, stream>>>(rowStart, cnt, srcs, inv, hw, b2, out, N);
}